// Round 3
// baseline (14.962 us; speedup 1.0000x reference)
//
#include <hip/hip_runtime.h>

#define IN_  1024
#define OUT_ 1024

typedef _Float16 f16x8 __attribute__((ext_vector_type(8)));
typedef float    f32x4 __attribute__((ext_vector_type(4)));

// ws layout (f16 elements):
//   Wn_pk [64 g][32 ks][64 l][8]  = 1,048,576 f16  @ offset 0
//   Wo_pk                          = 1,048,576 f16  @ offset 1048576
//   X_pk  [ 8 mq][32 ks][64 l][8] =   131,072 f16  @ offset 2097152
// Fragment convention (matches verified round-2 kernel):
//   row-in-tile = l&15, k-quadrant = l>>4, 8 contiguous k per lane.

__global__ __launch_bounds__(256, 4) void pack_f16(
    const float* __restrict__ x, const float* __restrict__ Wn,
    const float* __restrict__ Wo, _Float16* __restrict__ ws) {
  const int c = blockIdx.x * 256 + threadIdx.x;   // 16B-chunk id, 278528 total
  const float* src;
  _Float16* dst;
  if (c < 262144) {                 // W chunks: 2 mats x 131072
    const int mat = c >> 17;
    const int r   = c & 131071;     // (g*32+ks)*64 + l
    const int g   = r >> 11;
    const int ks  = (r >> 6) & 31;
    const int l   = r & 63;
    const int row  = g * 16 + (l & 15);
    const int col0 = ks * 32 + (l >> 4) * 8;
    src = (mat ? Wo : Wn) + (size_t)row * IN_ + col0;
    dst = ws + (size_t)mat * 1048576 + (size_t)r * 8;
  } else {                          // x chunks: 16384
    const int c2 = c - 262144;      // (mq*32+ks)*64 + l
    const int mq = c2 >> 11;
    const int ks = (c2 >> 6) & 31;
    const int l  = c2 & 63;
    const int row  = mq * 16 + (l & 15);
    const int col0 = ks * 32 + (l >> 4) * 8;
    src = x + (size_t)row * IN_ + col0;
    dst = ws + 2097152 + (size_t)c2 * 8;
  }
  const float4 u = ((const float4*)src)[0];
  const float4 v = ((const float4*)src)[1];
  f16x8 h = { (_Float16)u.x, (_Float16)u.y, (_Float16)u.z, (_Float16)u.w,
              (_Float16)v.x, (_Float16)v.y, (_Float16)v.z, (_Float16)v.w };
  *(f16x8*)dst = h;
}

// grid 512 = 8 mq (16 rows) x 64 g (16 cols, both GEMMs); 8 waves K-split 8
__global__ __launch_bounds__(512, 2) void dendritic_gemm(
    const _Float16* __restrict__ ws,
    const float* __restrict__ x,   // originals for exact edge terms
    const float* __restrict__ Wn,
    const float* __restrict__ bo,
    float* __restrict__ out) {
  const int tid = threadIdx.x;
  const int w   = tid >> 6;
  const int l   = tid & 63;
  const int g   = blockIdx.x & 63;   // b%8 == g%8 -> W-sharing blocks co-XCD
  const int mq  = blockIdx.x >> 6;

  const _Float16* Wn_pk = ws;
  const _Float16* Wo_pk = ws + 1048576;
  const _Float16* X_pk  = ws + 2097152;

  f32x4 accN = {0.f,0.f,0.f,0.f}, accO = {0.f,0.f,0.f,0.f};
#pragma unroll
  for (int i = 0; i < 4; ++i) {
    const int ks = w * 4 + i;
    f16x8 a  = *(const f16x8*)(X_pk  + (((size_t)mq * 32 + ks) * 64 + l) * 8);
    f16x8 bn = *(const f16x8*)(Wn_pk + (((size_t)g  * 32 + ks) * 64 + l) * 8);
    f16x8 bw = *(const f16x8*)(Wo_pk + (((size_t)g  * 32 + ks) * 64 + l) * 8);
    accN = __builtin_amdgcn_mfma_f32_16x16x32_f16(a, bn, accN, 0, 0, 0);
    accO = __builtin_amdgcn_mfma_f32_16x16x32_f16(a, bw, accO, 0, 0, 0);
  }

  __shared__ f32x4 red[8][2][64];   // 16 KiB
  red[w][0][l] = accN;
  red[w][1][l] = accO;
  __syncthreads();

  if (tid < 64) {
    f32x4 sN = red[0][0][tid], sO = red[0][1][tid];
#pragma unroll
    for (int q = 1; q < 8; ++q) { sN += red[q][0][tid]; sO += red[q][1][tid]; }

    const int n    = g * 16 + (tid & 15);
    const float bias = bo[n];
    const float wn0  = Wn[(size_t)n * IN_];
    const float wnL  = Wn[(size_t)n * IN_ + IN_ - 1];
#pragma unroll
    for (int r = 0; r < 4; ++r) {
      const int m = mq * 16 + (tid >> 4) * 4 + r;
      // conv1d([.5,.5],valid).sum == full dot - half of the two edge terms
      const float zN = sN[r] - 0.5f * (x[(size_t)m * IN_] * wn0 +
                                       x[(size_t)m * IN_ + IN_ - 1] * wnL);
      const float zO = sO[r] + bias;
      const float state = 1.f / (1.f + expf(-zO)) - 1.f;   // (-1,0)
      const float nm    = 2.f + state;                     // (1,2)
      const float kd    = exp2f(-nm);                      // 0.5^nm
      const float ca    = fmaxf(zN, 0.f);
      const float xn    = (ca > 0.f) ? exp2f(nm * log2f(ca)) : 0.f;
      out[(size_t)m * OUT_ + n] = xn / (kd + xn) + state;
    }
  }
}

extern "C" void kernel_launch(void* const* d_in, const int* in_sizes, int n_in,
                              void* d_out, int out_size, void* d_ws, size_t ws_size,
                              hipStream_t stream) {
  const float* x  = (const float*)d_in[0];
  const float* Wn = (const float*)d_in[1];
  const float* Wo = (const float*)d_in[2];
  const float* bo = (const float*)d_in[3];
  float* out = (float*)d_out;
  _Float16* ws = (_Float16*)d_ws;

  pack_f16<<<dim3(1088), dim3(256), 0, stream>>>(x, Wn, Wo, ws);
  dendritic_gemm<<<dim3(512), dim3(512), 0, stream>>>(ws, x, Wn, bo, out);
}

// Round 4
// 10.493 us; speedup vs baseline: 1.4259x; 1.4259x over previous
//
#include <hip/hip_runtime.h>

#define IN_  1024
#define OUT_ 1024

typedef _Float16 f16x8 __attribute__((ext_vector_type(8)));
typedef float    f32x4 __attribute__((ext_vector_type(4)));

// One block = 32 m-rows x 16 n-cols (both GEMMs). grid 256 = 4 mq x 64 g.
// 512 threads = 8 waves; per K-chunk of 256, wave w computes k-sub [w*32,w*32+32).
// LDS: sA f16[32][256] swizzled @0 (16KB), sB f16[2][16][256] @16384 (16KB),
//      red f32x4[8][2][2][64] @32768 (32KB).
__global__ __launch_bounds__(512, 1) void dendritic_fused(
    const float* __restrict__ x,   // [128,1024]
    const float* __restrict__ Wn,  // [1024,1024]
    const float* __restrict__ Wo,  // [1024,1024]
    const float* __restrict__ bo,  // [1024]
    float* __restrict__ out) {     // [128,1024]
  __shared__ __align__(16) char lds[65536];

  const int tid = threadIdx.x;
  const int w   = tid >> 6;
  const int l   = tid & 63;
  const int g   = blockIdx.x & 63;   // W-sharing blocks (same g) share b%8 -> co-XCD
  const int mq  = blockIdx.x >> 6;
  const int m0  = mq * 32;
  const int n0  = g * 16;

  // ---- staging geometry: unit i=0..3 handles 16-row band i, 8 f32 per unit ----
  const int c8 = tid & 31;           // 8-float column chunk within the 256-wide K-chunk
  const int rb = tid >> 5;           // row within band, 0..15
  const int swz = (rb & 7) << 4;
  const float* srcrow[4];
  srcrow[0] = x  + (size_t)(m0 + rb)      * IN_ + c8 * 8;
  srcrow[1] = x  + (size_t)(m0 + 16 + rb) * IN_ + c8 * 8;
  srcrow[2] = Wn + (size_t)(n0 + rb)      * IN_ + c8 * 8;
  srcrow[3] = Wo + (size_t)(n0 + rb)      * IN_ + c8 * 8;
  int dstoff[4];
  dstoff[0] = rb * 512                + ((c8 * 16) ^ swz);
  dstoff[1] = (16 + rb) * 512         + ((c8 * 16) ^ swz);
  dstoff[2] = 16384 + rb * 512        + ((c8 * 16) ^ swz);
  dstoff[3] = 16384 + 8192 + rb * 512 + ((c8 * 16) ^ swz);

  float4 v[4][2];

#define LOAD(ch)                                                         \
  _Pragma("unroll")                                                      \
  for (int i = 0; i < 4; ++i) {                                          \
    const float4* p = (const float4*)(srcrow[i] + (ch) * 256);           \
    v[i][0] = p[0];                                                      \
    v[i][1] = p[1];                                                      \
  }

#define WRITE(ch)                                                        \
  _Pragma("unroll")                                                      \
  for (int i = 0; i < 4; ++i) {                                          \
    f16x8 h = { (_Float16)v[i][0].x, (_Float16)v[i][0].y,                \
                (_Float16)v[i][0].z, (_Float16)v[i][0].w,                \
                (_Float16)v[i][1].x, (_Float16)v[i][1].y,                \
                (_Float16)v[i][1].z, (_Float16)v[i][1].w };              \
    if (i == 2) { /* fold conv edge: halve Wn col 0 and col 1023 */      \
      if ((ch) == 0 && c8 == 0)  h[0] = h[0] * (_Float16)0.5f;           \
      if ((ch) == 3 && c8 == 31) h[7] = h[7] * (_Float16)0.5f;           \
    }                                                                    \
    *(f16x8*)(lds + dstoff[i]) = h;                                      \
  }

  // ---- compute fragment addressing ----
  const int fr = l & 15;
  const int cb = ((w * 64 + (l >> 4) * 16) ^ ((fr & 7) << 4));
  const char* pa0 = lds + fr * 512 + cb;
  const char* pa1 = lds + (16 + fr) * 512 + cb;
  const char* pbn = lds + 16384 + fr * 512 + cb;
  const char* pbw = lds + 16384 + 8192 + fr * 512 + cb;

  f32x4 acc00 = {0.f,0.f,0.f,0.f}, acc01 = {0.f,0.f,0.f,0.f};
  f32x4 acc10 = {0.f,0.f,0.f,0.f}, acc11 = {0.f,0.f,0.f,0.f};

  // ---- pipelined main loop: issue-early (T14), single LDS buffer ----
  LOAD(0);
  WRITE(0);
  LOAD(1);
  __syncthreads();                     // chunk 0 staged
#pragma unroll
  for (int c = 0; c < 4; ++c) {
    f16x8 a0 = *(const f16x8*)pa0;
    f16x8 a1 = *(const f16x8*)pa1;
    f16x8 bn = *(const f16x8*)pbn;
    f16x8 bw = *(const f16x8*)pbw;
    acc00 = __builtin_amdgcn_mfma_f32_16x16x32_f16(a0, bn, acc00, 0, 0, 0);
    acc01 = __builtin_amdgcn_mfma_f32_16x16x32_f16(a0, bw, acc01, 0, 0, 0);
    acc10 = __builtin_amdgcn_mfma_f32_16x16x32_f16(a1, bn, acc10, 0, 0, 0);
    acc11 = __builtin_amdgcn_mfma_f32_16x16x32_f16(a1, bw, acc11, 0, 0, 0);
    __syncthreads();                   // everyone done reading chunk c
    if (c < 3) {
      WRITE(c + 1);
      if (c < 2) LOAD(c + 2);
      __syncthreads();                 // chunk c+1 staged
    }
  }

  // ---- cross-wave K reduction + fused epilogue ----
  *(f32x4*)(lds + 32768 + (((w * 2 + 0) * 2 + 0) * 64 + l) * 16) = acc00;
  *(f32x4*)(lds + 32768 + (((w * 2 + 0) * 2 + 1) * 64 + l) * 16) = acc01;
  *(f32x4*)(lds + 32768 + (((w * 2 + 1) * 2 + 0) * 64 + l) * 16) = acc10;
  *(f32x4*)(lds + 32768 + (((w * 2 + 1) * 2 + 1) * 64 + l) * 16) = acc11;
  __syncthreads();

  if (tid < 128) {
    const int mt = tid >> 6;
    const int ll = tid & 63;
    f32x4 sN = {0.f,0.f,0.f,0.f}, sO = {0.f,0.f,0.f,0.f};
#pragma unroll
    for (int q = 0; q < 8; ++q) {
      sN += *(const f32x4*)(lds + 32768 + (((q * 2 + mt) * 2 + 0) * 64 + ll) * 16);
      sO += *(const f32x4*)(lds + 32768 + (((q * 2 + mt) * 2 + 1) * 64 + ll) * 16);
    }
    const int n = n0 + (ll & 15);
    const float bias = bo[n];
#pragma unroll
    for (int r = 0; r < 4; ++r) {
      const int m = m0 + mt * 16 + (ll >> 4) * 4 + r;
      const float zN = sN[r];                              // edges pre-folded
      const float zO = sO[r] + bias;
      const float state = 1.f / (1.f + expf(-zO)) - 1.f;   // (-1,0)
      const float nm    = 2.f + state;                     // (1,2)
      const float kd    = exp2f(-nm);                      // 0.5^nm
      const float ca    = fmaxf(zN, 0.f);
      const float xn    = (ca > 0.f) ? exp2f(nm * log2f(ca)) : 0.f;
      out[(size_t)m * OUT_ + n] = xn / (kd + xn) + state;
    }
  }
#undef LOAD
#undef WRITE
}

extern "C" void kernel_launch(void* const* d_in, const int* in_sizes, int n_in,
                              void* d_out, int out_size, void* d_ws, size_t ws_size,
                              hipStream_t stream) {
  const float* x  = (const float*)d_in[0];
  const float* Wn = (const float*)d_in[1];
  const float* Wo = (const float*)d_in[2];
  const float* bo = (const float*)d_in[3];
  float* out = (float*)d_out;
  dendritic_fused<<<dim3(256), dim3(512), 0, stream>>>(x, Wn, Wo, bo, out);
}